// Round 1
// baseline (57.523 us; speedup 1.0000x reference)
//
#include <hip/hip_runtime.h>

// Math: output[n, h*28+w] = cos(pi * x[n,2h,2w] / (m[h,w] + 1e-8))
// where m[h,w] = max over n of max(x[n,2h,2w], x[n,2h,2w+1]).
// (Phases are unit-modulus and the CNOT perm swaps components 2,3 which
//  Z0 = [1,1,-1,-1] is invariant to, so params/phases/perm cancel exactly.)

namespace {

constexpr int IMG  = 56 * 56;   // 3136 floats per image
constexpr int HW   = 28 * 28;   // 784 outputs per image row-block
constexpr int NIMG = 8192;

__global__ void k_init(unsigned* __restrict__ m) {
    int i = blockIdx.x * blockDim.x + threadIdx.x;
    if (i < HW) m[i] = 0u;   // 0.0f bit pattern; inputs are uniform [0,1) >= 0
}

// Each block reduces n_per_block images; thread t owns hw slots {t, t+256, t+512, t+768}.
// Consecutive threads read consecutive float2 pairs within an even row -> coalesced.
__global__ __launch_bounds__(256) void k_reduce(const float* __restrict__ x,
                                                unsigned* __restrict__ m,
                                                int n_per_block) {
    const int t  = threadIdx.x;
    const int n0 = blockIdx.x * n_per_block;

    int   hw[4];
    int   off[4];
    float lm[4];
#pragma unroll
    for (int s = 0; s < 4; ++s) {
        hw[s] = t + s * 256;
        if (hw[s] < HW) {
            int h  = hw[s] / 28;
            int w  = hw[s] - h * 28;
            off[s] = h * 112 + w * 2;   // row 2h, cols (2w, 2w+1)
        } else {
            off[s] = -1;
        }
        lm[s] = 0.0f;
    }

    const float* base = x + (size_t)n0 * IMG;
    for (int n = 0; n < n_per_block; ++n, base += IMG) {
#pragma unroll
        for (int s = 0; s < 4; ++s) {
            if (off[s] >= 0) {
                float2 v = *(const float2*)(base + off[s]);
                lm[s] = fmaxf(lm[s], fmaxf(v.x, v.y));
            }
        }
    }

#pragma unroll
    for (int s = 0; s < 4; ++s) {
        if (off[s] >= 0) {
            // positive floats: uint bit-pattern compare == float compare
            atomicMax(m + hw[s], __float_as_uint(lm[s]));
        }
    }
}

// One thread -> two outputs (float2 write). Reads float4 (uses .x/.z = even cols).
// cos(pi*u) = v_cos_f32(u * 0.5) since v_cos takes revolutions; u in [0,1].
__global__ __launch_bounds__(256) void k_out(const float* __restrict__ x,
                                             const float* __restrict__ m,
                                             float* __restrict__ out) {
    int g  = blockIdx.x * 256 + threadIdx.x;   // [0, 8192*392)
    int n  = g / 392;
    int j  = g - n * 392;
    int h  = j / 14;
    int w2 = j - h * 14;

    float4 v  = *(const float4*)(x + (size_t)n * IMG + h * 112 + w2 * 4);
    float2 mm = *(const float2*)(m + h * 28 + w2 * 2);

    float r0 = v.x * (0.5f / (mm.x + 1e-8f));
    float r1 = v.z * (0.5f / (mm.y + 1e-8f));

    float2 o;
    o.x = __builtin_amdgcn_cosf(r0);
    o.y = __builtin_amdgcn_cosf(r1);

    *(float2*)(out + (size_t)n * 784 + h * 28 + w2 * 2) = o;
}

} // namespace

extern "C" void kernel_launch(void* const* d_in, const int* in_sizes, int n_in,
                              void* d_out, int out_size, void* d_ws, size_t ws_size,
                              hipStream_t stream) {
    const float* x   = (const float*)d_in[0];
    unsigned*    m   = (unsigned*)d_ws;          // 784 uint/float, reused as float
    float*       out = (float*)d_out;

    hipLaunchKernelGGL(k_init, dim3((HW + 255) / 256), dim3(256), 0, stream, m);

    constexpr int RBLOCKS = 512;                 // 16 images per block
    hipLaunchKernelGGL(k_reduce, dim3(RBLOCKS), dim3(256), 0, stream,
                       x, m, NIMG / RBLOCKS);

    const int total = NIMG * 392;                // 3,211,264 threads, 2 outputs each
    hipLaunchKernelGGL(k_out, dim3(total / 256), dim3(256), 0, stream,
                       x, (const float*)m, out);
}

// Round 3
// 45.704 us; speedup vs baseline: 1.2586x; 1.2586x over previous
//
#include <hip/hip_runtime.h>

// out[n, h*28+w] = cos(pi * x[n,2h,2w] / (m[h,w] + 1e-8)),
// m[h,w] = max_n max(x[n,2h,2w], x[n,2h,2w+1]).
// (Unit-modulus phases + CNOT perm leave the Z0 expectation = cos(t0);
//  params/phases/permutation cancel exactly.)
//
// 3 dispatches, atomic-light:
//  K1: 512 blocks x 16 images -> per-block partial maxima, PLAIN stores to
//      M[512][784]; block 0 zeroes mu. (No atomics in the hot pass.)
//  K2: 784 cols x 16 row-groups; each thread maxes 32 rows of M (coalesced),
//      one atomicMax per thread -> only 16 RMWs per address.
//  K3: cos(p0 * 0.5/(m+eps)) via v_cos (revolutions), float4 in / float2 out.

namespace {

constexpr int IMG  = 56 * 56;    // 3136 floats / image
constexpr int HW   = 28 * 28;    // 784 outputs / image
constexpr int NIMG = 8192;
constexpr int NB1  = 512;        // K1 blocks
constexpr int IPB  = NIMG / NB1; // 16 images per K1 block

__global__ __launch_bounds__(256) void k_partial(const float* __restrict__ x,
                                                 float* __restrict__ M,
                                                 unsigned* __restrict__ mu) {
    const int t = threadIdx.x;
    const int b = blockIdx.x;

    int   hw[4];
    int   off[4];
    float lm[4];
#pragma unroll
    for (int s = 0; s < 4; ++s) {
        hw[s] = t + s * 256;
        if (hw[s] < HW) {
            int h  = hw[s] / 28;
            int w  = hw[s] - h * 28;
            off[s] = h * 112 + w * 2;    // row 2h, cols (2w, 2w+1) — dense over even rows
        } else {
            off[s] = -1;
        }
        lm[s] = 0.0f;
    }

    if (b == 0) {   // zero mu for K2's atomics (ws is poisoned 0xAA; K1<K2 in stream order)
#pragma unroll
        for (int s = 0; s < 4; ++s)
            if (off[s] >= 0) mu[hw[s]] = 0u;
    }

    const float* base = x + (size_t)b * IPB * IMG;
#pragma unroll
    for (int n = 0; n < IPB; ++n) {
#pragma unroll
        for (int s = 0; s < 4; ++s) {
            if (off[s] >= 0) {
                float2 v = *(const float2*)(base + (size_t)n * IMG + off[s]);
                lm[s] = fmaxf(lm[s], fmaxf(v.x, v.y));
            }
        }
    }

#pragma unroll
    for (int s = 0; s < 4; ++s)
        if (off[s] >= 0) M[b * HW + hw[s]] = lm[s];
}

// 12544 threads = 784 cols x 16 row-groups of 32 rows.
__global__ __launch_bounds__(256) void k_final(const float* __restrict__ M,
                                               unsigned* __restrict__ mu) {
    int u = blockIdx.x * 256 + threadIdx.x;
    if (u >= HW * 16) return;
    int g   = u / HW;          // row-group
    int col = u - g * HW;      // consecutive threads -> consecutive cols (coalesced)
    float cm = 0.0f;
#pragma unroll
    for (int k = 0; k < 32; ++k)
        cm = fmaxf(cm, M[(g * 32 + k) * HW + col]);
    atomicMax(mu + col, __float_as_uint(cm));  // positive floats: uint cmp == float cmp
}

// One thread -> two outputs. cos(pi*u) = v_cos(u*0.5) [revolutions], u in [0,1].
__global__ __launch_bounds__(256) void k_out(const float* __restrict__ x,
                                             const float* __restrict__ m,
                                             float* __restrict__ out) {
    int g  = blockIdx.x * 256 + threadIdx.x;   // [0, 8192*392)
    int n  = g / 392;
    int j  = g - n * 392;
    int h  = j / 14;
    int w2 = j - h * 14;

    float4 v  = *(const float4*)(x + (size_t)n * IMG + h * 112 + w2 * 4);
    float2 mm = *(const float2*)(m + h * 28 + w2 * 2);

    float2 o;
    o.x = __builtin_amdgcn_cosf(v.x * (0.5f / (mm.x + 1e-8f)));
    o.y = __builtin_amdgcn_cosf(v.z * (0.5f / (mm.y + 1e-8f)));

    *(float2*)(out + (size_t)n * HW + h * 28 + w2 * 2) = o;
}

} // namespace

extern "C" void kernel_launch(void* const* d_in, const int* in_sizes, int n_in,
                              void* d_out, int out_size, void* d_ws, size_t ws_size,
                              hipStream_t stream) {
    const float* x   = (const float*)d_in[0];
    float*       M   = (float*)d_ws;                                   // 512*784 floats
    unsigned*    mu  = (unsigned*)((char*)d_ws + (size_t)NB1 * HW * 4);
    float*       out = (float*)d_out;

    hipLaunchKernelGGL(k_partial, dim3(NB1), dim3(256), 0, stream, x, M, mu);
    hipLaunchKernelGGL(k_final, dim3((HW * 16 + 255) / 256), dim3(256), 0, stream,
                       M, mu);
    hipLaunchKernelGGL(k_out, dim3(NIMG * 392 / 256), dim3(256), 0, stream,
                       x, (const float*)mu, out);
}

// Round 4
// 36.743 us; speedup vs baseline: 1.5655x; 1.2439x over previous
//
#include <hip/hip_runtime.h>

// out[n, h*28+w] = cos(pi * x[n,2h,2w] / (m[h,w] + 1e-8)),
// m[h,w] = max_n max(x[n,2h,2w], x[n,2h,2w+1]).
// (Unit-modulus phases + CNOT perm leave the Z0 expectation = cos(t0);
//  params/phases/permutation cancel exactly.)
//
// K1: 1024 blocks x 8 images. Each lane loads float4 = (p0,p1,p0,p1) for two
//     output positions -> float2 running maxima; plain float2 store to M.
// K2: 784 cols x 32 groups of 32 rows, coalesced; 32 atomicMax per col.
// K3: 4 outputs/thread: 2x float4 x-load, float4 out-store (1KB/wave).

namespace {

constexpr int IMG  = 3136;   // 56*56 floats / image
constexpr int HW   = 784;    // 28*28 outputs / image
constexpr int NIMG = 8192;
constexpr int NB1  = 1024;
constexpr int IPB  = NIMG / NB1;  // 8 images / K1 block
constexpr int NQ   = 392;         // float4 slots per image (14 per even row)

__global__ __launch_bounds__(256) void k_partial(const float* __restrict__ x,
                                                 float* __restrict__ M,
                                                 unsigned* __restrict__ mu) {
    const int t = threadIdx.x;
    const int b = blockIdx.x;

    if (b == 0) {   // zero mu for K2's atomics (ws poisoned 0xAA)
        for (int i = t; i < HW; i += 256) mu[i] = 0u;
    }

    // slot u covers float4 at row 2h, cols 4wq..4wq+3 = positions 2u, 2u+1
    const int h0 = t / 14,   w0 = t - h0 * 14;
    const int o0 = h0 * 112 + w0 * 4;
    const int u1 = t + 256;
    const int h1 = u1 / 14,  w1 = u1 - h1 * 14;
    const int o1 = h1 * 112 + w1 * 4;
    const bool a1 = (u1 < NQ);

    float2 lm0 = make_float2(0.f, 0.f);
    float2 lm1 = make_float2(0.f, 0.f);

    const float* base = x + (size_t)b * IPB * IMG;
#pragma unroll
    for (int n = 0; n < IPB; ++n) {
        const float* p = base + (size_t)n * IMG;
        float4 v = *(const float4*)(p + o0);
        lm0.x = fmaxf(lm0.x, fmaxf(v.x, v.y));
        lm0.y = fmaxf(lm0.y, fmaxf(v.z, v.w));
        if (a1) {
            float4 w = *(const float4*)(p + o1);
            lm1.x = fmaxf(lm1.x, fmaxf(w.x, w.y));
            lm1.y = fmaxf(lm1.y, fmaxf(w.z, w.w));
        }
    }

    *(float2*)(M + (size_t)b * HW + 2 * t) = lm0;
    if (a1) *(float2*)(M + (size_t)b * HW + 2 * u1) = lm1;
}

// 784 cols x 32 groups of 32 rows = 25088 threads (98 blocks, exact).
__global__ __launch_bounds__(256) void k_final(const float* __restrict__ M,
                                               unsigned* __restrict__ mu) {
    int u = blockIdx.x * 256 + threadIdx.x;
    int g   = u / HW;
    int col = u - g * HW;
    const float* p = M + (size_t)g * 32 * HW + col;
    float cm = 0.0f;
#pragma unroll
    for (int k = 0; k < 32; ++k)
        cm = fmaxf(cm, p[k * HW]);
    atomicMax(mu + col, __float_as_uint(cm));  // positive floats: uint cmp == float cmp
}

// 4 outputs/thread. cos(pi*u) = v_cos(u*0.5) [revolutions], u in [0,1].
// 8192*196 = 1,605,632 threads = 6272 blocks (exact).
__global__ __launch_bounds__(256) void k_out(const float* __restrict__ x,
                                             const float* __restrict__ mu,
                                             float* __restrict__ out) {
    int g  = blockIdx.x * 256 + threadIdx.x;
    int n  = g / 196;
    int j  = g - n * 196;       // output float4 index within image
    int h  = j / 7;
    int wq = j - h * 7;         // out cols 4wq..4wq+3

    const float* p = x + (size_t)n * IMG + h * 112 + 8 * wq;  // floats [8wq,8wq+8) of row 2h
    float4 va = *(const float4*)p;
    float4 vb = *(const float4*)(p + 4);

    const float* mp = mu + h * 28 + 4 * wq;
    float2 ma = *(const float2*)mp;        // mu[pos], mu[pos+1]
    float2 mb = *(const float2*)(mp + 2);  // mu[pos+2], mu[pos+3]

    float4 o;
    o.x = __builtin_amdgcn_cosf(va.x * (0.5f / (ma.x + 1e-8f)));
    o.y = __builtin_amdgcn_cosf(va.z * (0.5f / (ma.y + 1e-8f)));
    o.z = __builtin_amdgcn_cosf(vb.x * (0.5f / (mb.x + 1e-8f)));
    o.w = __builtin_amdgcn_cosf(vb.z * (0.5f / (mb.y + 1e-8f)));

    *(float4*)(out + (size_t)n * HW + 4 * j) = o;
}

} // namespace

extern "C" void kernel_launch(void* const* d_in, const int* in_sizes, int n_in,
                              void* d_out, int out_size, void* d_ws, size_t ws_size,
                              hipStream_t stream) {
    const float* x   = (const float*)d_in[0];
    float*       M   = (float*)d_ws;                                    // 1024*784 floats
    unsigned*    mu  = (unsigned*)((char*)d_ws + (size_t)NB1 * HW * 4); // 784 uints
    float*       out = (float*)d_out;

    hipLaunchKernelGGL(k_partial, dim3(NB1), dim3(256), 0, stream, x, M, mu);
    hipLaunchKernelGGL(k_final, dim3(HW * 32 / 256), dim3(256), 0, stream, M, mu);
    hipLaunchKernelGGL(k_out, dim3(NIMG * 196 / 256), dim3(256), 0, stream,
                       x, (const float*)mu, out);
}